// Round 13
// baseline (168.555 us; speedup 1.0000x reference)
//
#include <hip/hip_runtime.h>

#define T_SEQ   2048
#define NHEADS  12
#define DHEAD   64
#define WIN     16
#define WW      32
#define NWIN    128
#define DMODEL  768
#define NABCDE  3840
#define IGNORE_V (-1.0e6f)
#define PAD_K   72          // fp16 LDS row stride (144 B, 16B-aligned)
#define L2E64   0.022542110013890053f   // log2(e)/64
#define IGN_SC  (-22542.110013890053f)  // IGNORE_V * L2E64 (scaled domain)

typedef float f32x4 __attribute__((ext_vector_type(4)));
typedef _Float16 f16x8 __attribute__((ext_vector_type(8)));

__device__ __forceinline__ short f2h(float f) {
    union { _Float16 h; short s; } u;
    u.h = (_Float16)f;                  // v_cvt_f16_f32 (RNE)
    return u.s;
}

__device__ __forceinline__ void gload_lds16(const short* g, short* l) {
    __builtin_amdgcn_global_load_lds(
        (const __attribute__((address_space(1))) void*)g,
        (__attribute__((address_space(3))) void*)l,
        16, 0, 0);
}

// ---------------------------------------------------------------------------
// merged prep: [0,1536) cast x -> xh; [1536,4416) transpose W_abcde -> Wt;
// [4416,4992) transpose W_O -> WOt.  (all outputs fp16)
// ---------------------------------------------------------------------------
__global__ __launch_bounds__(256) void prep_kernel(
    const float* __restrict__ x, const float* __restrict__ W_abcde,
    const float* __restrict__ W_O,
    short* __restrict__ xh, short* __restrict__ Wt, short* __restrict__ WOt)
{
    __shared__ float tile[32][33];
    const int blk = blockIdx.x;
    const int tid = threadIdx.x;

    if (blk < 1536) {
        int i = (blk * 256 + tid) * 8;
        float4 a = *reinterpret_cast<const float4*>(&x[i]);
        float4 b = *reinterpret_cast<const float4*>(&x[i + 4]);
        union { short s[8]; uint4 u; } r;
        r.s[0] = f2h(a.x); r.s[1] = f2h(a.y); r.s[2] = f2h(a.z); r.s[3] = f2h(a.w);
        r.s[4] = f2h(b.x); r.s[5] = f2h(b.y); r.s[6] = f2h(b.z); r.s[7] = f2h(b.w);
        *reinterpret_cast<uint4*>(&xh[i]) = r.u;
        return;
    }
    const float* W; short* Wo; int N, bx, by;
    if (blk < 4416) {
        int t = blk - 1536;
        W = W_abcde; Wo = Wt; N = NABCDE;
        bx = (t % 120) * 32; by = (t / 120) * 32;
    } else {
        int t = blk - 4416;
        W = W_O; Wo = WOt; N = DMODEL;
        bx = (t % 24) * 32; by = (t / 24) * 32;
    }
    const int tx = tid & 31, ty = tid >> 5;
#pragma unroll
    for (int r = 0; r < 32; r += 8)
        tile[ty + r][tx] = W[(size_t)(by + ty + r) * N + bx + tx];
    __syncthreads();
#pragma unroll
    for (int r = 0; r < 32; r += 8)
        Wo[(size_t)(bx + ty + r) * DMODEL + by + tx] = f2h(tile[tx][ty + r]);
}

// ---------------------------------------------------------------------------
// GEMM1: fp16 MFMA, 256x256 tile, 512 threads (8 waves 2Mx4N), BK=32,
// ring-4 LDS, counted vmcnt pipeline, single barrier per K-iter, XOR
// chunk-swizzle. (round-10 verified)
// ---------------------------------------------------------------------------
__global__ __launch_bounds__(512, 2) void gemm1_kernel(
    const short* __restrict__ A, const short* __restrict__ Bt,
    const float* __restrict__ bias, short* __restrict__ C,
    int M, int N, int K)
{
    __shared__ short LT[4][2][8192];   // [ring][A|B][256 rows x 32 cols fp16]

    const int tid  = threadIdx.x;
    const int wave = tid >> 6;
    const int lane = tid & 63;

    int bid = blockIdx.x;
    int t = (bid & 7) * 30 + (bid >> 3);   // bijective XCD swizzle (240 = 8*30)
    const int bm = (t / 15) * 256;
    const int bn = (t % 15) * 256;

    const int wr = wave >> 2;              // 0..1  (M half: 128 rows)
    const int wc = wave & 3;               // 0..3  (N quarter: 64 cols)
    const int fm = lane & 15;
    const int ko = lane >> 4;              // 0..3 (K chunk of 8)
    const int kswz = ko ^ ((lane >> 2) & 3);   // read-side XOR chunk swizzle
    const int w32 = wave * 32;

    const int srow = lane >> 2;                              // 0..15
    const int scc  = ((lane & 3) ^ ((lane >> 4) & 3)) * 8;   // pre-swizzled src chunk
    const short* gA[2]; const short* gB[2];
#pragma unroll
    for (int j = 0; j < 2; ++j) {
        gA[j] = A  + (size_t)(bm + w32 + j * 16 + srow) * K + scc;
        gB[j] = Bt + (size_t)(bn + w32 + j * 16 + srow) * K + scc;
    }

    f32x4 acc[8][4];
#pragma unroll
    for (int mi = 0; mi < 8; ++mi)
#pragma unroll
        for (int ni = 0; ni < 4; ++ni) acc[mi][ni] = (f32x4){0.f, 0.f, 0.f, 0.f};

    // prologue: stage K-tiles 0,1,2  (12 loads/thread in flight)
#pragma unroll
    for (int kt = 0; kt < 3; ++kt) {
#pragma unroll
        for (int j = 0; j < 2; ++j) {
            gload_lds16(gA[j] + kt * 32, &LT[kt][0][(w32 + j * 16) * 32]);
            gload_lds16(gB[j] + kt * 32, &LT[kt][1][(w32 + j * 16) * 32]);
        }
    }

    const int NKT = K >> 5;        // 24 K-tiles
    const int nkm = NKT - 3;       // 21 staged iterations

#define G1_STEP(KB, VMC, DOSTAGE, KS)                                          \
    {                                                                          \
        asm volatile("s_waitcnt vmcnt(" #VMC ")" ::: "memory");                \
        __builtin_amdgcn_s_barrier();                                          \
        asm volatile("" ::: "memory");                                         \
        if (DOSTAGE) {                                                         \
            int sb_ = (KS) & 3;                                                \
            _Pragma("unroll")                                                  \
            for (int j = 0; j < 2; ++j) {                                      \
                gload_lds16(gA[j] + (KS) * 32, &LT[sb_][0][(w32 + j * 16) * 32]); \
                gload_lds16(gB[j] + (KS) * 32, &LT[sb_][1][(w32 + j * 16) * 32]); \
            }                                                                  \
        }                                                                      \
        const short* Ab_ = &LT[(KB)][0][0];                                    \
        const short* Bb_ = &LT[(KB)][1][0];                                    \
        f16x8 af_[8], bf_[4];                                                  \
        _Pragma("unroll")                                                      \
        for (int mi = 0; mi < 8; ++mi)                                         \
            af_[mi] = *reinterpret_cast<const f16x8*>(                         \
                &Ab_[(wr * 128 + mi * 16 + fm) * 32 + kswz * 8]);              \
        _Pragma("unroll")                                                      \
        for (int ni = 0; ni < 4; ++ni)                                         \
            bf_[ni] = *reinterpret_cast<const f16x8*>(                         \
                &Bb_[(wc * 64 + ni * 16 + fm) * 32 + kswz * 8]);               \
        __builtin_amdgcn_s_setprio(1);                                         \
        _Pragma("unroll")                                                      \
        for (int mi = 0; mi < 8; ++mi)                                         \
            _Pragma("unroll")                                                  \
            for (int ni = 0; ni < 4; ++ni)                                     \
                acc[mi][ni] = __builtin_amdgcn_mfma_f32_16x16x32_f16(          \
                    af_[mi], bf_[ni], acc[mi][ni], 0, 0, 0);                   \
        __builtin_amdgcn_s_setprio(0);                                         \
    }

    for (int k = 0; k < nkm; ++k) {
        G1_STEP(k & 3, 8, true, k + 3);
    }
    G1_STEP(nkm & 3, 8, false, 0);
    G1_STEP((nkm + 1) & 3, 4, false, 0);
    G1_STEP((nkm + 2) & 3, 0, false, 0);
#undef G1_STEP

    // epilogue: bias + fp16 pack, coalesced via LDS in two 128-row halves
    float bv[4];
#pragma unroll
    for (int ni = 0; ni < 4; ++ni)
        bv[ni] = bias[bn + wc * 64 + ni * 16 + fm];

    short* cb = &LT[0][0][0];               // 128 rows x 256 cols = 64 KiB
#pragma unroll
    for (int half = 0; half < 2; ++half) {
        __syncthreads();
        if (wr == half) {
#pragma unroll
            for (int mi = 0; mi < 8; ++mi) {
#pragma unroll
                for (int r = 0; r < 4; ++r) {
                    int lrow = mi * 16 + ko * 4 + r;      // 0..127
#pragma unroll
                    for (int ni = 0; ni < 4; ++ni)
                        cb[lrow * 256 + wc * 64 + ni * 16 + fm] =
                            f2h(acc[mi][ni][r] + bv[ni]);
                }
            }
        }
        __syncthreads();
#pragma unroll
        for (int q = 0; q < 8; ++q) {
            int f = tid + q * 512;
            int row = f >> 5, c16 = (f & 31) * 8;
            *reinterpret_cast<uint4*>(
                &C[(size_t)(bm + half * 128 + row) * N + bn + c16]) =
                *reinterpret_cast<const uint4*>(&cb[row * 256 + c16]);
        }
    }
}

// ---------------------------------------------------------------------------
// GEMM2: fp16 MFMA, 64x64 tile, BK=64 (high-TLP, 768 blocks), fp32 out.
// ---------------------------------------------------------------------------
__global__ __launch_bounds__(256) void gemm_h16_64(
    const short* __restrict__ A, const short* __restrict__ Bt,
    const float* __restrict__ bias, float* __restrict__ C,
    int M, int N, int K)
{
    __shared__ short As[2][64 * 32];
    __shared__ short Bs[2][64 * 32];

    const int tid  = threadIdx.x;
    const int wave = tid >> 6;
    const int lane = tid & 63;
    const int bm = blockIdx.y * 64;
    const int bn = blockIdx.x * 64;

    const int st_row = lane >> 2;
    const int st_col = (lane & 3) * 8;
    const int fr_m = lane & 15;
    const int fr_k = (lane >> 4) * 8;
    const int wm = wave * 16;

    const short* gsrc[4];
    short* ldst[4];
#pragma unroll
    for (int j = 0; j < 4; ++j) {
        int c = wave * 4 + j;
        if (c < 8) {
            int kt = c >> 2, rg = c & 3;
            gsrc[j] = A + (size_t)(bm + rg * 16 + st_row) * K + kt * 32 + st_col;
            ldst[j] = &As[kt][(rg * 16) * 32];
        } else {
            int cb = c - 8;
            int kt = cb >> 2, rg = cb & 3;
            gsrc[j] = Bt + (size_t)(bn + rg * 16 + st_row) * K + kt * 32 + st_col;
            ldst[j] = &Bs[kt][(rg * 16) * 32];
        }
    }

    f32x4 acc[4];
#pragma unroll
    for (int ni = 0; ni < 4; ++ni) acc[ni] = (f32x4){0.f, 0.f, 0.f, 0.f};

    for (int k0 = 0; k0 < K; k0 += 64) {
#pragma unroll
        for (int j = 0; j < 4; ++j) gload_lds16(gsrc[j] + k0, ldst[j]);
        __syncthreads();

#pragma unroll
        for (int kt = 0; kt < 2; ++kt) {
            f16x8 af = *reinterpret_cast<const f16x8*>(
                &As[kt][(wm + fr_m) * 32 + fr_k]);
#pragma unroll
            for (int ni = 0; ni < 4; ++ni) {
                f16x8 bf = *reinterpret_cast<const f16x8*>(
                    &Bs[kt][(ni * 16 + fr_m) * 32 + fr_k]);
                acc[ni] = __builtin_amdgcn_mfma_f32_16x16x32_f16(
                    af, bf, acc[ni], 0, 0, 0);
            }
        }
        __syncthreads();
    }

    float bv[4];
#pragma unroll
    for (int ni = 0; ni < 4; ++ni)
        bv[ni] = bias[bn + ni * 16 + (lane & 15)];
    int rbase = bm + wm + (lane >> 4) * 4;
#pragma unroll
    for (int r = 0; r < 4; ++r) {
        size_t off = (size_t)(rbase + r) * N + bn + (lane & 15);
#pragma unroll
        for (int ni = 0; ni < 4; ++ni)
            C[off + ni * 16] = acc[ni][r] + bv[ni];
    }
}

// ---------------------------------------------------------------------------
// Windowed trittention, fp16. 2 windows per block (round-12 version).
// THIS ROUND: launched TWICE (idempotent) for timing attribution.
// ---------------------------------------------------------------------------
__global__ __launch_bounds__(512) void attn_kernel(
    const short* __restrict__ abcde, short* __restrict__ z)
{
    // 1536 blocks = 8 XCD * 192, bijective swizzle; blk = bh*64 + jp
    const int bid = blockIdx.x;
    const int blk = (bid & 7) * 192 + (bid >> 3);
    const int jp = blk & 63;           // window-pair index
    const int bh = blk >> 6;
    const int b  = bh / NHEADS;
    const int h  = bh % NHEADS;
    const int n0 = jp * 2;             // first window of the pair

    __shared__ short sc[32 * PAD_K];    // c rows [n0*16, n0*16+32)
    __shared__ short sa[48 * PAD_K];    // look-back rows [n0*16-16, n0*16+32)
    __shared__ short sb[48 * PAD_K];
    __shared__ short sd[48 * PAD_K];
    __shared__ short se[48 * PAD_K];
    __shared__ short epA[32 * PAD_K];   // per window: 16 rows (pm | pl)
    __shared__ float sinv[32];

    const int tid = threadIdx.x;
    const size_t rowbase = ((size_t)b * T_SEQ) * NABCDE;
    const int hd = h * DHEAD;

    // ---- staging: c (threads 0..255), look-back 48 rows (threads 0..383)
    if (tid < 256) {
        int row = tid >> 3, ch = (tid & 7) * 8;
        *reinterpret_cast<uint4*>(&sc[row * PAD_K + ch]) =
            *reinterpret_cast<const uint4*>(
                &abcde[rowbase + (size_t)(n0 * WIN + row) * NABCDE + 2 * DMODEL + hd + ch]);
    }
    if (tid < 384) {
        int row = tid >> 3, ch = (tid & 7) * 8;
        int t = n0 * WIN - WIN + row;
        uint4 va = {0u, 0u, 0u, 0u}, vb = va, vd = va, ve = va;
        if (t >= 0) {
            size_t base = rowbase + (size_t)t * NABCDE + hd + ch;
            va = *reinterpret_cast<const uint4*>(&abcde[base + 0 * DMODEL]);
            vb = *reinterpret_cast<const uint4*>(&abcde[base + 1 * DMODEL]);
            vd = *reinterpret_cast<const uint4*>(&abcde[base + 3 * DMODEL]);
            ve = *reinterpret_cast<const uint4*>(&abcde[base + 4 * DMODEL]);
        }
        *reinterpret_cast<uint4*>(&sa[row * PAD_K + ch]) = va;
        *reinterpret_cast<uint4*>(&sb[row * PAD_K + ch]) = vb;
        *reinterpret_cast<uint4*>(&sd[row * PAD_K + ch]) = vd;
        *reinterpret_cast<uint4*>(&se[row * PAD_K + ch]) = ve;
    }
    __syncthreads();   // B1

    const int wv = tid >> 6;           // 0..7
    const int w  = wv >> 2;            // window select (0 or 1)
    const int wvl = wv & 3;            // wave-in-window
    const int n  = n0 + w;
    const int lane = tid & 63;
    const int lc = lane & 15;
    const int ko = lane >> 4;
    const int lb = w * 16;             // look-back row offset for this window
    const int ew = w * 16;             // epA/sinv row offset

    // ---- c fragment pre-scaled by L2E64 (packed fp16); b fragments raw
    f16x8 cfrag[2];
    f16x8 bfrag[2][2];
#pragma unroll
    for (int kt = 0; kt < 2; ++kt) {
        cfrag[kt] = *reinterpret_cast<const f16x8*>(
            &sc[(ew + wvl * 4 + (lc & 3)) * PAD_K + kt * 32 + ko * 8]) * (_Float16)L2E64;
        bfrag[0][kt] = *reinterpret_cast<const f16x8*>(&sb[(lb + lc) * PAD_K + kt * 32 + ko * 8]);
        bfrag[1][kt] = *reinterpret_cast<const f16x8*>(&sb[(lb + 16 + lc) * PAD_K + kt * 32 + ko * 8]);
    }

    f32x4 acc[8][2];
#pragma unroll
    for (int mt = 0; mt < 8; ++mt) {
        acc[mt][0] = (f32x4){0.f, 0.f, 0.f, 0.f};
        acc[mt][1] = (f32x4){0.f, 0.f, 0.f, 0.f};
    }
    __builtin_amdgcn_s_setprio(1);
#pragma unroll
    for (int mt = 0; mt < 8; ++mt) {
#pragma unroll
        for (int kt = 0; kt < 2; ++kt) {
            f16x8 ar = *reinterpret_cast<const f16x8*>(
                &sa[(lb + mt * 4 + (lc >> 2)) * PAD_K + kt * 32 + ko * 8]);
            f16x8 pa = cfrag[kt] * ar;            // -> v_pk_mul_f16 x4
            acc[mt][0] = __builtin_amdgcn_mfma_f32_16x16x32_f16(pa, bfrag[0][kt], acc[mt][0], 0, 0, 0);
            acc[mt][1] = __builtin_amdgcn_mfma_f32_16x16x32_f16(pa, bfrag[1][kt], acc[mt][1], 0, 0, 0);
        }
    }
    __builtin_amdgcn_s_setprio(0);

    if (n != 0) {
        // ---- fast path: fused mask + no-max softmax numerator (pre-scaled).
#pragma unroll
        for (int lt = 0; lt < 2; ++lt) {
            const int l = lt * 16 + lc;
#pragma unroll
            for (int mt = 0; mt < 8; ++mt) {
                const bool mgt = l > (mt * 4 + ko);
#pragma unroll
                for (int reg = 0; reg < 4; ++reg) {
                    const bool keep = mgt && (wvl * 4 + reg + WIN >= l);
                    float p = __builtin_amdgcn_exp2f(acc[mt][lt][reg]);
                    acc[mt][lt][reg] = keep ? p : 0.0f;
                }
            }
        }
    } else {
        // ---- n==0 (only waves w=0 of block blk==0): IGNORE + max-shift.
        int bbl_h[2]; bool keepL[2][4];
#pragma unroll
        for (int lt = 0; lt < 2; ++lt) {
            int l = lt * 16 + lc;
            bbl_h[lt] = (l < WIN) ? 0 : (l - WIN);
#pragma unroll
            for (int reg = 0; reg < 4; ++reg)
                keepL[lt][reg] = (wvl * 4 + reg) >= bbl_h[lt];
        }
#pragma unroll
        for (int mt = 0; mt < 8; ++mt) {
            int m = mt * 4 + ko;
            int bbm = (m < WIN) ? 0 : (m - WIN);
#pragma unroll
            for (int lt = 0; lt < 2; ++lt) {
                bool mgt = bbl_h[lt] > bbm;
#pragma unroll
                for (int reg = 0; reg < 4; ++reg) {
                    float s = acc[mt][lt][reg];
                    if (!(keepL[lt][reg] && mgt) || s == 0.0f)
                        acc[mt][lt][reg] = IGN_SC;
                }
            }
        }
        float mx[4] = {-3.4e38f, -3.4e38f, -3.4e38f, -3.4e38f};
#pragma unroll
        for (int mt = 0; mt < 8; ++mt)
#pragma unroll
            for (int lt = 0; lt < 2; ++lt)
#pragma unroll
                for (int reg = 0; reg < 4; ++reg)
                    mx[reg] = fmaxf(mx[reg], acc[mt][lt][reg]);
#pragma unroll
        for (int reg = 0; reg < 4; ++reg) {
#pragma unroll
            for (int off = 1; off < 64; off <<= 1)
                mx[reg] = fmaxf(mx[reg], __shfl_xor(mx[reg], off, 64));
        }
#pragma unroll
        for (int mt = 0; mt < 8; ++mt)
#pragma unroll
            for (int lt = 0; lt < 2; ++lt)
#pragma unroll
                for (int reg = 0; reg < 4; ++reg)
                    acc[mt][lt][reg] = __builtin_amdgcn_exp2f(
                        acc[mt][lt][reg] - mx[reg]);
    }

    // ---- pl (col-marginal over m) + epA cols 32..63; keep plv for sm
    float plv[2][4];
#pragma unroll
    for (int lt = 0; lt < 2; ++lt) {
#pragma unroll
        for (int reg = 0; reg < 4; ++reg) {
            float p = acc[0][lt][reg];
#pragma unroll
            for (int mt = 1; mt < 8; ++mt) p += acc[mt][lt][reg];
            p += __shfl_xor(p, 16, 64);
            p += __shfl_xor(p, 32, 64);
            plv[lt][reg] = p;
        }
        float w1  = (ko & 1) ? plv[lt][1] : plv[lt][0];
        float w2 = (ko & 1) ? plv[lt][3] : plv[lt][2];
        float ww = (ko & 2) ? w2 : w1;
        epA[(ew + wvl * 4 + ko) * PAD_K + 32 + lt * 16 + lc] = f2h(ww);
    }

    // ---- sm[i] = sum_l pl[i][l]
    {
        float s[4];
#pragma unroll
        for (int reg = 0; reg < 4; ++reg) {
            float t = plv[0][reg] + plv[1][reg];
            t += __shfl_xor(t, 1, 64);
            t += __shfl_xor(t, 2, 64);
            t += __shfl_xor(t, 4, 64);
            t += __shfl_xor(t, 8, 64);
            s[reg] = t;
        }
        if (lane == 0) {
#pragma unroll
            for (int reg = 0; reg < 4; ++reg) sinv[ew + wvl * 4 + reg] = 1.0f / s[reg];
        }
    }

    // ---- pm via pair-tree over lc; write epA cols 0..31
    {
        float v8[8][4];
#pragma unroll
        for (int mt = 0; mt < 8; ++mt)
#pragma unroll
            for (int reg = 0; reg < 4; ++reg)
                v8[mt][reg] = acc[mt][0][reg] + acc[mt][1][reg];

        const bool s0 = lane & 1, s1 = lane & 2, s2 = lane & 4, s3 = lane & 8;
        float r1[4][4];
#pragma unroll
        for (int m2 = 0; m2 < 4; ++m2)
#pragma unroll
            for (int reg = 0; reg < 4; ++reg) {
                float u = v8[2 * m2][reg], wq = v8[2 * m2 + 1][reg];
                float a = s0 ? wq : u;
                float s = s0 ? u : wq;
                r1[m2][reg] = a + __shfl_xor(s, 1, 64);
            }
        float r2[2][4];
#pragma unroll
        for (int m4 = 0; m4 < 2; ++m4)
#pragma unroll
            for (int reg = 0; reg < 4; ++reg) {
                float u = r1[2 * m4][reg], wq = r1[2 * m4 + 1][reg];
                float a = s1 ? wq : u;
                float s = s1 ? u : wq;
                r2[m4][reg] = a + __shfl_xor(s, 2, 64);
            }
        float r3[4];
#pragma unroll
        for (int reg = 0; reg < 4; ++reg) {
            float u = r2[0][reg], wq = r2[1][reg];
            float a = s2 ? wq : u;
            float s = s2 ? u : wq;
            r3[reg] = a + __shfl_xor(s, 4, 64);
        }
        float a0 = s3 ? r3[1] : r3[0];
        float q0 = s3 ? r3[0] : r3[1];
        float g0 = a0 + __shfl_xor(q0, 8, 64);
        float a1 = s3 ? r3[3] : r3[2];
        float q1 = s3 ? r3[2] : r3[3];
        float g1 = a1 + __shfl_xor(q1, 8, 64);

        int mcol = (lc & 7) * 4 + ko;
        int ib = ew + wvl * 4 + (lc >> 3);
        epA[ib * PAD_K + mcol]       = f2h(g0);
        epA[(ib + 2) * PAD_K + mcol] = f2h(g1);
    }

    // ---- epilogue B-frags from sd/se (pre-barrier; dd = wvl*16+lc)
    const int dd = wvl * 16 + lc;
    f16x8 bd, be;
    {
        unsigned dv[8], ev[8];
#pragma unroll
        for (int j = 0; j < 8; ++j) {
            dv[j] = *reinterpret_cast<const unsigned short*>(&sd[(lb + ko * 8 + j) * PAD_K + dd]);
            ev[j] = *reinterpret_cast<const unsigned short*>(&se[(lb + ko * 8 + j) * PAD_K + dd]);
        }
        union { unsigned u[4]; f16x8 v; } td, te;
#pragma unroll
        for (int j = 0; j < 4; ++j) {
            td.u[j] = __builtin_amdgcn_perm(dv[2 * j + 1], dv[2 * j], 0x05040100);
            te.u[j] = __builtin_amdgcn_perm(ev[2 * j + 1], ev[2 * j], 0x05040100);
        }
        bd = td.v; be = te.v;
    }
    __syncthreads();   // B2

    // ---- cooperative epilogue MFMA
    f16x8 apm = *reinterpret_cast<const f16x8*>(&epA[(ew + lc) * PAD_K + ko * 8]);
    f16x8 apl = *reinterpret_cast<const f16x8*>(&epA[(ew + lc) * PAD_K + 32 + ko * 8]);
    f32x4 zacc = (f32x4){0.f, 0.f, 0.f, 0.f};
    __builtin_amdgcn_s_setprio(1);
    zacc = __builtin_amdgcn_mfma_f32_16x16x32_f16(apm, bd, zacc, 0, 0, 0);
    zacc = __builtin_amdgcn_mfma_f32_16x16x32_f16(apl, be, zacc, 0, 0, 0);
    __builtin_amdgcn_s_setprio(0);

    // ---- z repack in LDS (sd dead after B2): 32 rows x 64 cols
    short* zs = sd;
#pragma unroll
    for (int reg = 0; reg < 4; ++reg) {
        int i = ew + ko * 4 + reg;        // 0..31 (both windows)
        zs[i * 64 + dd] = f2h(zacc[reg] * sinv[i]);
    }
    __syncthreads();   // B3
    {
        int row = tid >> 4;            // 0..31
        int ch  = (tid & 15) * 4;      // 4 shorts = 8B
        *reinterpret_cast<uint2*>(
            &z[((size_t)b * T_SEQ + n0 * WIN + row) * (NHEADS * DHEAD) + hd + ch]) =
            *reinterpret_cast<const uint2*>(&zs[row * 64 + ch]);
    }
}

// ---------------------------------------------------------------------------
extern "C" void kernel_launch(void* const* d_in, const int* in_sizes, int n_in,
                              void* d_out, int out_size, void* d_ws, size_t ws_size,
                              hipStream_t stream) {
    const float* x        = (const float*)d_in[0];
    const float* W_abcde  = (const float*)d_in[1];
    const float* b_abcde  = (const float*)d_in[2];
    const float* W_O      = (const float*)d_in[3];
    const float* b_O      = (const float*)d_in[4];
    float* out = (float*)d_out;

    char* ws = (char*)d_ws;
    short* abcde = (short*)ws;                                  // 4096x3840 fp16 (31.5 MB)
    short* xh    = (short*)(ws + (size_t)31457280);             // 4096x768 fp16, reused as zb
    short* Wt    = (short*)(ws + (size_t)31457280 + 6291456);   // 3840x768 fp16
    short* WOt   = (short*)(ws + (size_t)31457280 + 6291456 + 5898240); // 768x768 fp16
    short* zb    = xh;

    const int M = 2 * T_SEQ;  // 4096

    prep_kernel<<<dim3(4992), dim3(256), 0, stream>>>(
        x, W_abcde, W_O, xh, Wt, WOt);

    gemm1_kernel<<<dim3(240), dim3(512), 0, stream>>>(
        xh, Wt, b_abcde, abcde, M, NABCDE, DMODEL);

    // ---- ATTRIBUTION EXPERIMENT: attn launched twice (idempotent).
    // attn_dur = this round's dur_us - 146.1 (round 12). Pre-committed:
    // >=25 us -> attack attn serialization next; <=12 us -> near floor.
    attn_kernel<<<dim3(NHEADS * NWIN), dim3(512), 0, stream>>>(abcde, zb);
    attn_kernel<<<dim3(NHEADS * NWIN), dim3(512), 0, stream>>>(abcde, zb);

    gemm_h16_64<<<dim3(DMODEL / 64, M / 64), dim3(256), 0, stream>>>(
        zb, WOt, b_O, out, M, DMODEL, DMODEL);
}

// Round 14
// 145.639 us; speedup vs baseline: 1.1573x; 1.1573x over previous
//
#include <hip/hip_runtime.h>

#define T_SEQ   2048
#define NHEADS  12
#define DHEAD   64
#define WIN     16
#define WW      32
#define NWIN    128
#define DMODEL  768
#define NABCDE  3840
#define IGNORE_V (-1.0e6f)
#define PAD_K   72          // fp16 LDS row stride (144 B, 16B-aligned)
#define PAD_R   52          // transposed sd/se row-count stride (104 B, 8B-aligned)
#define L2E64   0.022542110013890053f   // log2(e)/64
#define IGN_SC  (-22542.110013890053f)  // IGNORE_V * L2E64 (scaled domain)

typedef float f32x4 __attribute__((ext_vector_type(4)));
typedef _Float16 f16x8 __attribute__((ext_vector_type(8)));

__device__ __forceinline__ short f2h(float f) {
    union { _Float16 h; short s; } u;
    u.h = (_Float16)f;                  // v_cvt_f16_f32 (RNE)
    return u.s;
}

__device__ __forceinline__ void gload_lds16(const short* g, short* l) {
    __builtin_amdgcn_global_load_lds(
        (const __attribute__((address_space(1))) void*)g,
        (__attribute__((address_space(3))) void*)l,
        16, 0, 0);
}

// ---------------------------------------------------------------------------
// merged prep: [0,1536) cast x -> xh; [1536,4416) transpose W_abcde -> Wt;
// [4416,4992) transpose W_O -> WOt.  (all outputs fp16)
// ---------------------------------------------------------------------------
__global__ __launch_bounds__(256) void prep_kernel(
    const float* __restrict__ x, const float* __restrict__ W_abcde,
    const float* __restrict__ W_O,
    short* __restrict__ xh, short* __restrict__ Wt, short* __restrict__ WOt)
{
    __shared__ float tile[32][33];
    const int blk = blockIdx.x;
    const int tid = threadIdx.x;

    if (blk < 1536) {
        int i = (blk * 256 + tid) * 8;
        float4 a = *reinterpret_cast<const float4*>(&x[i]);
        float4 b = *reinterpret_cast<const float4*>(&x[i + 4]);
        union { short s[8]; uint4 u; } r;
        r.s[0] = f2h(a.x); r.s[1] = f2h(a.y); r.s[2] = f2h(a.z); r.s[3] = f2h(a.w);
        r.s[4] = f2h(b.x); r.s[5] = f2h(b.y); r.s[6] = f2h(b.z); r.s[7] = f2h(b.w);
        *reinterpret_cast<uint4*>(&xh[i]) = r.u;
        return;
    }
    const float* W; short* Wo; int N, bx, by;
    if (blk < 4416) {
        int t = blk - 1536;
        W = W_abcde; Wo = Wt; N = NABCDE;
        bx = (t % 120) * 32; by = (t / 120) * 32;
    } else {
        int t = blk - 4416;
        W = W_O; Wo = WOt; N = DMODEL;
        bx = (t % 24) * 32; by = (t / 24) * 32;
    }
    const int tx = tid & 31, ty = tid >> 5;
#pragma unroll
    for (int r = 0; r < 32; r += 8)
        tile[ty + r][tx] = W[(size_t)(by + ty + r) * N + bx + tx];
    __syncthreads();
#pragma unroll
    for (int r = 0; r < 32; r += 8)
        Wo[(size_t)(bx + ty + r) * DMODEL + by + tx] = f2h(tile[tx][ty + r]);
}

// ---------------------------------------------------------------------------
// GEMM1: fp16 MFMA, 256x256 tile, 512 threads (8 waves 2Mx4N), BK=32,
// ring-4 LDS, counted vmcnt pipeline, single barrier per K-iter, XOR
// chunk-swizzle. (round-10 verified)
// ---------------------------------------------------------------------------
__global__ __launch_bounds__(512, 2) void gemm1_kernel(
    const short* __restrict__ A, const short* __restrict__ Bt,
    const float* __restrict__ bias, short* __restrict__ C,
    int M, int N, int K)
{
    __shared__ short LT[4][2][8192];   // [ring][A|B][256 rows x 32 cols fp16]

    const int tid  = threadIdx.x;
    const int wave = tid >> 6;
    const int lane = tid & 63;

    int bid = blockIdx.x;
    int t = (bid & 7) * 30 + (bid >> 3);   // bijective XCD swizzle (240 = 8*30)
    const int bm = (t / 15) * 256;
    const int bn = (t % 15) * 256;

    const int wr = wave >> 2;              // 0..1  (M half: 128 rows)
    const int wc = wave & 3;               // 0..3  (N quarter: 64 cols)
    const int fm = lane & 15;
    const int ko = lane >> 4;              // 0..3 (K chunk of 8)
    const int kswz = ko ^ ((lane >> 2) & 3);   // read-side XOR chunk swizzle
    const int w32 = wave * 32;

    const int srow = lane >> 2;                              // 0..15
    const int scc  = ((lane & 3) ^ ((lane >> 4) & 3)) * 8;   // pre-swizzled src chunk
    const short* gA[2]; const short* gB[2];
#pragma unroll
    for (int j = 0; j < 2; ++j) {
        gA[j] = A  + (size_t)(bm + w32 + j * 16 + srow) * K + scc;
        gB[j] = Bt + (size_t)(bn + w32 + j * 16 + srow) * K + scc;
    }

    f32x4 acc[8][4];
#pragma unroll
    for (int mi = 0; mi < 8; ++mi)
#pragma unroll
        for (int ni = 0; ni < 4; ++ni) acc[mi][ni] = (f32x4){0.f, 0.f, 0.f, 0.f};

    // prologue: stage K-tiles 0,1,2  (12 loads/thread in flight)
#pragma unroll
    for (int kt = 0; kt < 3; ++kt) {
#pragma unroll
        for (int j = 0; j < 2; ++j) {
            gload_lds16(gA[j] + kt * 32, &LT[kt][0][(w32 + j * 16) * 32]);
            gload_lds16(gB[j] + kt * 32, &LT[kt][1][(w32 + j * 16) * 32]);
        }
    }

    const int NKT = K >> 5;        // 24 K-tiles
    const int nkm = NKT - 3;       // 21 staged iterations

#define G1_STEP(KB, VMC, DOSTAGE, KS)                                          \
    {                                                                          \
        asm volatile("s_waitcnt vmcnt(" #VMC ")" ::: "memory");                \
        __builtin_amdgcn_s_barrier();                                          \
        asm volatile("" ::: "memory");                                         \
        if (DOSTAGE) {                                                         \
            int sb_ = (KS) & 3;                                                \
            _Pragma("unroll")                                                  \
            for (int j = 0; j < 2; ++j) {                                      \
                gload_lds16(gA[j] + (KS) * 32, &LT[sb_][0][(w32 + j * 16) * 32]); \
                gload_lds16(gB[j] + (KS) * 32, &LT[sb_][1][(w32 + j * 16) * 32]); \
            }                                                                  \
        }                                                                      \
        const short* Ab_ = &LT[(KB)][0][0];                                    \
        const short* Bb_ = &LT[(KB)][1][0];                                    \
        f16x8 af_[8], bf_[4];                                                  \
        _Pragma("unroll")                                                      \
        for (int mi = 0; mi < 8; ++mi)                                         \
            af_[mi] = *reinterpret_cast<const f16x8*>(                         \
                &Ab_[(wr * 128 + mi * 16 + fm) * 32 + kswz * 8]);              \
        _Pragma("unroll")                                                      \
        for (int ni = 0; ni < 4; ++ni)                                         \
            bf_[ni] = *reinterpret_cast<const f16x8*>(                         \
                &Bb_[(wc * 64 + ni * 16 + fm) * 32 + kswz * 8]);               \
        __builtin_amdgcn_s_setprio(1);                                         \
        _Pragma("unroll")                                                      \
        for (int mi = 0; mi < 8; ++mi)                                         \
            _Pragma("unroll")                                                  \
            for (int ni = 0; ni < 4; ++ni)                                     \
                acc[mi][ni] = __builtin_amdgcn_mfma_f32_16x16x32_f16(          \
                    af_[mi], bf_[ni], acc[mi][ni], 0, 0, 0);                   \
        __builtin_amdgcn_s_setprio(0);                                         \
    }

    for (int k = 0; k < nkm; ++k) {
        G1_STEP(k & 3, 8, true, k + 3);
    }
    G1_STEP(nkm & 3, 8, false, 0);
    G1_STEP((nkm + 1) & 3, 4, false, 0);
    G1_STEP((nkm + 2) & 3, 0, false, 0);
#undef G1_STEP

    // epilogue: bias + fp16 pack, coalesced via LDS in two 128-row halves
    float bv[4];
#pragma unroll
    for (int ni = 0; ni < 4; ++ni)
        bv[ni] = bias[bn + wc * 64 + ni * 16 + fm];

    short* cb = &LT[0][0][0];               // 128 rows x 256 cols = 64 KiB
#pragma unroll
    for (int half = 0; half < 2; ++half) {
        __syncthreads();
        if (wr == half) {
#pragma unroll
            for (int mi = 0; mi < 8; ++mi) {
#pragma unroll
                for (int r = 0; r < 4; ++r) {
                    int lrow = mi * 16 + ko * 4 + r;      // 0..127
#pragma unroll
                    for (int ni = 0; ni < 4; ++ni)
                        cb[lrow * 256 + wc * 64 + ni * 16 + fm] =
                            f2h(acc[mi][ni][r] + bv[ni]);
                }
            }
        }
        __syncthreads();
#pragma unroll
        for (int q = 0; q < 8; ++q) {
            int f = tid + q * 512;
            int row = f >> 5, c16 = (f & 31) * 8;
            *reinterpret_cast<uint4*>(
                &C[(size_t)(bm + half * 128 + row) * N + bn + c16]) =
                *reinterpret_cast<const uint4*>(&cb[row * 256 + c16]);
        }
    }
}

// ---------------------------------------------------------------------------
// GEMM2: fp16 MFMA, 64x64 tile, BK=64 (high-TLP, 768 blocks), fp32 out.
// ---------------------------------------------------------------------------
__global__ __launch_bounds__(256) void gemm_h16_64(
    const short* __restrict__ A, const short* __restrict__ Bt,
    const float* __restrict__ bias, float* __restrict__ C,
    int M, int N, int K)
{
    __shared__ short As[2][64 * 32];
    __shared__ short Bs[2][64 * 32];

    const int tid  = threadIdx.x;
    const int wave = tid >> 6;
    const int lane = tid & 63;
    const int bm = blockIdx.y * 64;
    const int bn = blockIdx.x * 64;

    const int st_row = lane >> 2;
    const int st_col = (lane & 3) * 8;
    const int fr_m = lane & 15;
    const int fr_k = (lane >> 4) * 8;
    const int wm = wave * 16;

    const short* gsrc[4];
    short* ldst[4];
#pragma unroll
    for (int j = 0; j < 4; ++j) {
        int c = wave * 4 + j;
        if (c < 8) {
            int kt = c >> 2, rg = c & 3;
            gsrc[j] = A + (size_t)(bm + rg * 16 + st_row) * K + kt * 32 + st_col;
            ldst[j] = &As[kt][(rg * 16) * 32];
        } else {
            int cb = c - 8;
            int kt = cb >> 2, rg = cb & 3;
            gsrc[j] = Bt + (size_t)(bn + rg * 16 + st_row) * K + kt * 32 + st_col;
            ldst[j] = &Bs[kt][(rg * 16) * 32];
        }
    }

    f32x4 acc[4];
#pragma unroll
    for (int ni = 0; ni < 4; ++ni) acc[ni] = (f32x4){0.f, 0.f, 0.f, 0.f};

    for (int k0 = 0; k0 < K; k0 += 64) {
#pragma unroll
        for (int j = 0; j < 4; ++j) gload_lds16(gsrc[j] + k0, ldst[j]);
        __syncthreads();

#pragma unroll
        for (int kt = 0; kt < 2; ++kt) {
            f16x8 af = *reinterpret_cast<const f16x8*>(
                &As[kt][(wm + fr_m) * 32 + fr_k]);
#pragma unroll
            for (int ni = 0; ni < 4; ++ni) {
                f16x8 bf = *reinterpret_cast<const f16x8*>(
                    &Bs[kt][(ni * 16 + fr_m) * 32 + fr_k]);
                acc[ni] = __builtin_amdgcn_mfma_f32_16x16x32_f16(
                    af, bf, acc[ni], 0, 0, 0);
            }
        }
        __syncthreads();
    }

    float bv[4];
#pragma unroll
    for (int ni = 0; ni < 4; ++ni)
        bv[ni] = bias[bn + ni * 16 + (lane & 15)];
    int rbase = bm + wm + (lane >> 4) * 4;
#pragma unroll
    for (int r = 0; r < 4; ++r) {
        size_t off = (size_t)(rbase + r) * N + bn + (lane & 15);
#pragma unroll
        for (int ni = 0; ni < 4; ++ni)
            C[off + ni * 16] = acc[ni][r] + bv[ni];
    }
}

// ---------------------------------------------------------------------------
// Windowed trittention, fp16, 2 windows per block. THIS ROUND: sd/se stored
// DIMENSION-MAJOR (sdT[64][PAD_R]) so the epilogue B-frag build is 2x
// ds_read_b64 per matrix (was 16 scalar 8-way-conflicted ds_read_u16 + 8
// perms). Staging pays 8 scalar ds_write_b16 per array per thread.
// ---------------------------------------------------------------------------
__global__ __launch_bounds__(512) void attn_kernel(
    const short* __restrict__ abcde, short* __restrict__ z)
{
    // 1536 blocks = 8 XCD * 192, bijective swizzle; blk = bh*64 + jp
    const int bid = blockIdx.x;
    const int blk = (bid & 7) * 192 + (bid >> 3);
    const int jp = blk & 63;           // window-pair index
    const int bh = blk >> 6;
    const int b  = bh / NHEADS;
    const int h  = bh % NHEADS;
    const int n0 = jp * 2;             // first window of the pair

    __shared__ short sc[32 * PAD_K];    // c rows [n0*16, n0*16+32)
    __shared__ short sa[48 * PAD_K];    // look-back rows [n0*16-16, n0*16+32)
    __shared__ short sb[48 * PAD_K];
    __shared__ short sdT[64 * PAD_R];   // d transposed: [dim][row]
    __shared__ short seT[64 * PAD_R];   // e transposed: [dim][row]
    __shared__ short epA[32 * PAD_K];   // per window: 16 rows (pm | pl)
    __shared__ float sinv[32];

    const int tid = threadIdx.x;
    const size_t rowbase = ((size_t)b * T_SEQ) * NABCDE;
    const int hd = h * DHEAD;

    // ---- staging: c (threads 0..255), look-back 48 rows (threads 0..383)
    if (tid < 256) {
        int row = tid >> 3, ch = (tid & 7) * 8;
        *reinterpret_cast<uint4*>(&sc[row * PAD_K + ch]) =
            *reinterpret_cast<const uint4*>(
                &abcde[rowbase + (size_t)(n0 * WIN + row) * NABCDE + 2 * DMODEL + hd + ch]);
    }
    if (tid < 384) {
        int row = tid >> 3, ch = (tid & 7) * 8;
        int t = n0 * WIN - WIN + row;
        uint4 va = {0u, 0u, 0u, 0u}, vb = va, vd = va, ve = va;
        if (t >= 0) {
            size_t base = rowbase + (size_t)t * NABCDE + hd + ch;
            va = *reinterpret_cast<const uint4*>(&abcde[base + 0 * DMODEL]);
            vb = *reinterpret_cast<const uint4*>(&abcde[base + 1 * DMODEL]);
            vd = *reinterpret_cast<const uint4*>(&abcde[base + 3 * DMODEL]);
            ve = *reinterpret_cast<const uint4*>(&abcde[base + 4 * DMODEL]);
        }
        *reinterpret_cast<uint4*>(&sa[row * PAD_K + ch]) = va;
        *reinterpret_cast<uint4*>(&sb[row * PAD_K + ch]) = vb;
        union { uint4 u; short s[8]; } Dv, Ev;
        Dv.u = vd; Ev.u = ve;
#pragma unroll
        for (int q = 0; q < 8; ++q) {
            sdT[(ch + q) * PAD_R + row] = Dv.s[q];
            seT[(ch + q) * PAD_R + row] = Ev.s[q];
        }
    }
    __syncthreads();   // B1

    const int wv = tid >> 6;           // 0..7
    const int w  = wv >> 2;            // window select (0 or 1)
    const int wvl = wv & 3;            // wave-in-window
    const int n  = n0 + w;
    const int lane = tid & 63;
    const int lc = lane & 15;
    const int ko = lane >> 4;
    const int lb = w * 16;             // look-back row offset for this window
    const int ew = w * 16;             // epA/sinv row offset

    // ---- c fragment pre-scaled by L2E64 (packed fp16); b fragments raw
    f16x8 cfrag[2];
    f16x8 bfrag[2][2];
#pragma unroll
    for (int kt = 0; kt < 2; ++kt) {
        cfrag[kt] = *reinterpret_cast<const f16x8*>(
            &sc[(ew + wvl * 4 + (lc & 3)) * PAD_K + kt * 32 + ko * 8]) * (_Float16)L2E64;
        bfrag[0][kt] = *reinterpret_cast<const f16x8*>(&sb[(lb + lc) * PAD_K + kt * 32 + ko * 8]);
        bfrag[1][kt] = *reinterpret_cast<const f16x8*>(&sb[(lb + 16 + lc) * PAD_K + kt * 32 + ko * 8]);
    }

    f32x4 acc[8][2];
#pragma unroll
    for (int mt = 0; mt < 8; ++mt) {
        acc[mt][0] = (f32x4){0.f, 0.f, 0.f, 0.f};
        acc[mt][1] = (f32x4){0.f, 0.f, 0.f, 0.f};
    }
    __builtin_amdgcn_s_setprio(1);
#pragma unroll
    for (int mt = 0; mt < 8; ++mt) {
#pragma unroll
        for (int kt = 0; kt < 2; ++kt) {
            f16x8 ar = *reinterpret_cast<const f16x8*>(
                &sa[(lb + mt * 4 + (lc >> 2)) * PAD_K + kt * 32 + ko * 8]);
            f16x8 pa = cfrag[kt] * ar;            // -> v_pk_mul_f16 x4
            acc[mt][0] = __builtin_amdgcn_mfma_f32_16x16x32_f16(pa, bfrag[0][kt], acc[mt][0], 0, 0, 0);
            acc[mt][1] = __builtin_amdgcn_mfma_f32_16x16x32_f16(pa, bfrag[1][kt], acc[mt][1], 0, 0, 0);
        }
    }
    __builtin_amdgcn_s_setprio(0);

    if (n != 0) {
        // ---- fast path: fused mask + no-max softmax numerator (pre-scaled).
#pragma unroll
        for (int lt = 0; lt < 2; ++lt) {
            const int l = lt * 16 + lc;
#pragma unroll
            for (int mt = 0; mt < 8; ++mt) {
                const bool mgt = l > (mt * 4 + ko);
#pragma unroll
                for (int reg = 0; reg < 4; ++reg) {
                    const bool keep = mgt && (wvl * 4 + reg + WIN >= l);
                    float p = __builtin_amdgcn_exp2f(acc[mt][lt][reg]);
                    acc[mt][lt][reg] = keep ? p : 0.0f;
                }
            }
        }
    } else {
        // ---- n==0 (only waves w=0 of block blk==0): IGNORE + max-shift.
        int bbl_h[2]; bool keepL[2][4];
#pragma unroll
        for (int lt = 0; lt < 2; ++lt) {
            int l = lt * 16 + lc;
            bbl_h[lt] = (l < WIN) ? 0 : (l - WIN);
#pragma unroll
            for (int reg = 0; reg < 4; ++reg)
                keepL[lt][reg] = (wvl * 4 + reg) >= bbl_h[lt];
        }
#pragma unroll
        for (int mt = 0; mt < 8; ++mt) {
            int m = mt * 4 + ko;
            int bbm = (m < WIN) ? 0 : (m - WIN);
#pragma unroll
            for (int lt = 0; lt < 2; ++lt) {
                bool mgt = bbl_h[lt] > bbm;
#pragma unroll
                for (int reg = 0; reg < 4; ++reg) {
                    float s = acc[mt][lt][reg];
                    if (!(keepL[lt][reg] && mgt) || s == 0.0f)
                        acc[mt][lt][reg] = IGN_SC;
                }
            }
        }
        float mx[4] = {-3.4e38f, -3.4e38f, -3.4e38f, -3.4e38f};
#pragma unroll
        for (int mt = 0; mt < 8; ++mt)
#pragma unroll
            for (int lt = 0; lt < 2; ++lt)
#pragma unroll
                for (int reg = 0; reg < 4; ++reg)
                    mx[reg] = fmaxf(mx[reg], acc[mt][lt][reg]);
#pragma unroll
        for (int reg = 0; reg < 4; ++reg) {
#pragma unroll
            for (int off = 1; off < 64; off <<= 1)
                mx[reg] = fmaxf(mx[reg], __shfl_xor(mx[reg], off, 64));
        }
#pragma unroll
        for (int mt = 0; mt < 8; ++mt)
#pragma unroll
            for (int lt = 0; lt < 2; ++lt)
#pragma unroll
                for (int reg = 0; reg < 4; ++reg)
                    acc[mt][lt][reg] = __builtin_amdgcn_exp2f(
                        acc[mt][lt][reg] - mx[reg]);
    }

    // ---- pl (col-marginal over m) + epA cols 32..63; keep plv for sm
    float plv[2][4];
#pragma unroll
    for (int lt = 0; lt < 2; ++lt) {
#pragma unroll
        for (int reg = 0; reg < 4; ++reg) {
            float p = acc[0][lt][reg];
#pragma unroll
            for (int mt = 1; mt < 8; ++mt) p += acc[mt][lt][reg];
            p += __shfl_xor(p, 16, 64);
            p += __shfl_xor(p, 32, 64);
            plv[lt][reg] = p;
        }
        float w1  = (ko & 1) ? plv[lt][1] : plv[lt][0];
        float w2 = (ko & 1) ? plv[lt][3] : plv[lt][2];
        float ww = (ko & 2) ? w2 : w1;
        epA[(ew + wvl * 4 + ko) * PAD_K + 32 + lt * 16 + lc] = f2h(ww);
    }

    // ---- sm[i] = sum_l pl[i][l]
    {
        float s[4];
#pragma unroll
        for (int reg = 0; reg < 4; ++reg) {
            float t = plv[0][reg] + plv[1][reg];
            t += __shfl_xor(t, 1, 64);
            t += __shfl_xor(t, 2, 64);
            t += __shfl_xor(t, 4, 64);
            t += __shfl_xor(t, 8, 64);
            s[reg] = t;
        }
        if (lane == 0) {
#pragma unroll
            for (int reg = 0; reg < 4; ++reg) sinv[ew + wvl * 4 + reg] = 1.0f / s[reg];
        }
    }

    // ---- pm via pair-tree over lc; write epA cols 0..31
    {
        float v8[8][4];
#pragma unroll
        for (int mt = 0; mt < 8; ++mt)
#pragma unroll
            for (int reg = 0; reg < 4; ++reg)
                v8[mt][reg] = acc[mt][0][reg] + acc[mt][1][reg];

        const bool s0 = lane & 1, s1 = lane & 2, s2 = lane & 4, s3 = lane & 8;
        float r1[4][4];
#pragma unroll
        for (int m2 = 0; m2 < 4; ++m2)
#pragma unroll
            for (int reg = 0; reg < 4; ++reg) {
                float u = v8[2 * m2][reg], wq = v8[2 * m2 + 1][reg];
                float a = s0 ? wq : u;
                float s = s0 ? u : wq;
                r1[m2][reg] = a + __shfl_xor(s, 1, 64);
            }
        float r2[2][4];
#pragma unroll
        for (int m4 = 0; m4 < 2; ++m4)
#pragma unroll
            for (int reg = 0; reg < 4; ++reg) {
                float u = r1[2 * m4][reg], wq = r1[2 * m4 + 1][reg];
                float a = s1 ? wq : u;
                float s = s1 ? u : wq;
                r2[m4][reg] = a + __shfl_xor(s, 2, 64);
            }
        float r3[4];
#pragma unroll
        for (int reg = 0; reg < 4; ++reg) {
            float u = r2[0][reg], wq = r2[1][reg];
            float a = s2 ? wq : u;
            float s = s2 ? u : wq;
            r3[reg] = a + __shfl_xor(s, 4, 64);
        }
        float a0 = s3 ? r3[1] : r3[0];
        float q0 = s3 ? r3[0] : r3[1];
        float g0 = a0 + __shfl_xor(q0, 8, 64);
        float a1 = s3 ? r3[3] : r3[2];
        float q1 = s3 ? r3[2] : r3[3];
        float g1 = a1 + __shfl_xor(q1, 8, 64);

        int mcol = (lc & 7) * 4 + ko;
        int ib = ew + wvl * 4 + (lc >> 3);
        epA[ib * PAD_K + mcol]       = f2h(g0);
        epA[(ib + 2) * PAD_K + mcol] = f2h(g1);
    }

    // ---- epilogue B-frags from transposed sdT/seT: 2x ds_read_b64 each.
    // bd[j] = d[lb + ko*8 + j][dd] = sdT[dd*PAD_R + lb + ko*8 + j]
    const int dd = wvl * 16 + lc;
    f16x8 bd, be;
    {
        const int base = dd * PAD_R + lb + ko * 8;
        union { uint2 u2[2]; f16x8 v; } td, te;
        td.u2[0] = *reinterpret_cast<const uint2*>(&sdT[base]);
        td.u2[1] = *reinterpret_cast<const uint2*>(&sdT[base + 4]);
        te.u2[0] = *reinterpret_cast<const uint2*>(&seT[base]);
        te.u2[1] = *reinterpret_cast<const uint2*>(&seT[base + 4]);
        bd = td.v; be = te.v;
    }
    __syncthreads();   // B2

    // ---- cooperative epilogue MFMA
    f16x8 apm = *reinterpret_cast<const f16x8*>(&epA[(ew + lc) * PAD_K + ko * 8]);
    f16x8 apl = *reinterpret_cast<const f16x8*>(&epA[(ew + lc) * PAD_K + 32 + ko * 8]);
    f32x4 zacc = (f32x4){0.f, 0.f, 0.f, 0.f};
    __builtin_amdgcn_s_setprio(1);
    zacc = __builtin_amdgcn_mfma_f32_16x16x32_f16(apm, bd, zacc, 0, 0, 0);
    zacc = __builtin_amdgcn_mfma_f32_16x16x32_f16(apl, be, zacc, 0, 0, 0);
    __builtin_amdgcn_s_setprio(0);

    // ---- z repack in LDS (sdT memory dead after B2): 32 rows x 64 cols
    short* zs = sdT;
#pragma unroll
    for (int reg = 0; reg < 4; ++reg) {
        int i = ew + ko * 4 + reg;        // 0..31 (both windows)
        zs[i * 64 + dd] = f2h(zacc[reg] * sinv[i]);
    }
    __syncthreads();   // B3
    {
        int row = tid >> 4;            // 0..31
        int ch  = (tid & 15) * 4;      // 4 shorts = 8B
        *reinterpret_cast<uint2*>(
            &z[((size_t)b * T_SEQ + n0 * WIN + row) * (NHEADS * DHEAD) + hd + ch]) =
            *reinterpret_cast<const uint2*>(&zs[row * 64 + ch]);
    }
}

// ---------------------------------------------------------------------------
extern "C" void kernel_launch(void* const* d_in, const int* in_sizes, int n_in,
                              void* d_out, int out_size, void* d_ws, size_t ws_size,
                              hipStream_t stream) {
    const float* x        = (const float*)d_in[0];
    const float* W_abcde  = (const float*)d_in[1];
    const float* b_abcde  = (const float*)d_in[2];
    const float* W_O      = (const float*)d_in[3];
    const float* b_O      = (const float*)d_in[4];
    float* out = (float*)d_out;

    char* ws = (char*)d_ws;
    short* abcde = (short*)ws;                                  // 4096x3840 fp16 (31.5 MB)
    short* xh    = (short*)(ws + (size_t)31457280);             // 4096x768 fp16, reused as zb
    short* Wt    = (short*)(ws + (size_t)31457280 + 6291456);   // 3840x768 fp16
    short* WOt   = (short*)(ws + (size_t)31457280 + 6291456 + 5898240); // 768x768 fp16
    short* zb    = xh;

    const int M = 2 * T_SEQ;  // 4096

    prep_kernel<<<dim3(4992), dim3(256), 0, stream>>>(
        x, W_abcde, W_O, xh, Wt, WOt);

    gemm1_kernel<<<dim3(240), dim3(512), 0, stream>>>(
        xh, Wt, b_abcde, abcde, M, NABCDE, DMODEL);

    attn_kernel<<<dim3(NHEADS * NWIN), dim3(512), 0, stream>>>(abcde, zb);

    gemm_h16_64<<<dim3(DMODEL / 64, M / 64), dim3(256), 0, stream>>>(
        zb, WOt, b_O, out, M, DMODEL, DMODEL);
}